// Round 1
// baseline (891.038 us; speedup 1.0000x reference)
//
#include <hip/hip_runtime.h>
#include <math.h>

#define SCALE 0.0625f   // 256^-0.5

// token t (window order: [nd][p][pix]) -> row in x/out layout [nd][H][W]
__device__ __forceinline__ int token_to_xrow(int t) {
    int nd  = t / 3136;          // 49*64
    int r   = t % 3136;
    int p   = r >> 6;            // window 0..48
    int pix = r & 63;            // pixel 0..63
    int j = p / 7, i = p % 7;
    int hh = pix >> 3, ww = pix & 7;
    return nd * 3136 + (j * 8 + hh) * 56 + (i * 8 + ww);
}

// ---------------------------------------------------------------------------
// K1: qkv = gather_window_rows(x) @ Wqkv + bqkv
//     q  -> q_ws  [t][256]   kv -> kv_ws [t][512]   (unshifted window order)
// ---------------------------------------------------------------------------
__global__ __launch_bounds__(256) void k_qkv(const float* __restrict__ x,
                                             const float* __restrict__ Wqkv,
                                             const float* __restrict__ bqkv,
                                             float* __restrict__ q_ws,
                                             float* __restrict__ kv_ws) {
    __shared__ float As[16 * 68];   // [k][m], stride 68 (float4-aligned, low conflict)
    __shared__ float Bs[16 * 64];   // [k][n]
    const int tid = threadIdx.x;
    const int m0 = blockIdx.y * 64;   // token tile
    const int n0 = blockIdx.x * 64;   // out-channel tile

    const int ar = tid >> 2;            // 0..63 row
    const int ak = (tid & 3) * 4;       // 0,4,8,12
    const int arow = token_to_xrow(m0 + ar);
    const float* aptr = x + (size_t)arow * 256 + ak;

    const int bk = tid >> 4;            // 0..15
    const int bn = (tid & 15) * 4;      // 0..60
    const float* bptr = Wqkv + (size_t)bk * 768 + n0 + bn;

    const int ty = tid >> 4, tx = tid & 15;
    float acc[4][4] = {};

    for (int kt = 0; kt < 256; kt += 16) {
        float4 av = *(const float4*)(aptr + kt);
        float4 bv = *(const float4*)(bptr + (size_t)kt * 768);
        __syncthreads();
        As[(ak + 0) * 68 + ar] = av.x;
        As[(ak + 1) * 68 + ar] = av.y;
        As[(ak + 2) * 68 + ar] = av.z;
        As[(ak + 3) * 68 + ar] = av.w;
        *(float4*)&Bs[bk * 64 + bn] = bv;
        __syncthreads();
#pragma unroll
        for (int kk = 0; kk < 16; ++kk) {
            float4 a4 = *(const float4*)&As[kk * 68 + ty * 4];
            float4 b4 = *(const float4*)&Bs[kk * 64 + tx * 4];
            float a[4] = {a4.x, a4.y, a4.z, a4.w};
            float b[4] = {b4.x, b4.y, b4.z, b4.w};
#pragma unroll
            for (int ii = 0; ii < 4; ++ii)
#pragma unroll
                for (int jj = 0; jj < 4; ++jj) acc[ii][jj] += a[ii] * b[jj];
        }
    }
#pragma unroll
    for (int ii = 0; ii < 4; ++ii) {
        int t = m0 + ty * 4 + ii;
#pragma unroll
        for (int jj = 0; jj < 4; ++jj) {
            int col = n0 + tx * 4 + jj;
            float v = acc[ii][jj] + bqkv[col];
            if (col < 256) q_ws[(size_t)t * 256 + col] = v;
            else           kv_ws[(size_t)t * 512 + (col - 256)] = v;
        }
    }
}

// ---------------------------------------------------------------------------
// K2: per-window means (unshifted; shift handled by consumer indexing)
// ---------------------------------------------------------------------------
__global__ __launch_bounds__(256) void k_means(const float* __restrict__ q_ws,
                                               const float* __restrict__ kv_ws,
                                               float* __restrict__ qwin,
                                               float* __restrict__ kwin) {
    const int b = blockIdx.x;     // nd*49 + p
    const int c = threadIdx.x;    // 0..255
    const float* qb = q_ws + (size_t)b * 64 * 256;
    const float* kb = kv_ws + (size_t)b * 64 * 512;
    float s1 = 0.f, s2 = 0.f;
    for (int pix = 0; pix < 64; ++pix) {
        s1 += qb[(size_t)pix * 256 + c];
        s2 += kb[(size_t)pix * 512 + c];
    }
    qwin[b * 256 + c] = s1 * (1.f / 64.f);
    kwin[b * 256 + c] = s2 * (1.f / 64.f);
}

// ---------------------------------------------------------------------------
// K3: routing logits + top-4 (one wave per (nd,p))
// ---------------------------------------------------------------------------
__global__ __launch_bounds__(64) void k_route(const float* __restrict__ qwin,
                                              const float* __restrict__ kwin,
                                              int* __restrict__ ridx) {
    const int b = blockIdx.x;                 // nd*49 + p
    const int nd = b / 49;
    const int ndkv = ((nd & 7) == 7) ? nd : nd + 1;   // frame shift d->min(d+1,7)
    const int t = threadIdx.x;
    __shared__ float qs[256];
    for (int i = t; i < 256; i += 64) qs[i] = qwin[b * 256 + i];
    __syncthreads();
    float logit = -INFINITY;
    if (t < 49) {
        const float* kr = kwin + ((size_t)ndkv * 49 + t) * 256;
        float s = 0.f;
        for (int c = 0; c < 256; ++c) s += qs[c] * kr[c];
        logit = s;   // positive scale doesn't change ordering
    }
    for (int sel = 0; sel < 4; ++sel) {
        float v = logit;
        int ix = t;
        for (int off = 32; off > 0; off >>= 1) {
            float ov = __shfl_xor(v, off);
            int   oi = __shfl_xor(ix, off);
            if (ov > v || (ov == v && oi < ix)) { v = ov; ix = oi; }
        }
        if (t == 0) ridx[b * 4 + sel] = ix;
        if (t == ix) logit = -INFINITY;
    }
}

// ---------------------------------------------------------------------------
// K4: per (nd, p, head) attention over the 4 routed windows (256 keys).
//     Writes result in-place over q_ws (block reads its q slice to LDS first;
//     heads own disjoint 32-channel ranges).
// ---------------------------------------------------------------------------
__global__ __launch_bounds__(256) void k_attn(float* qa,                     // q_ws, in/out
                                              const float* __restrict__ kv_ws,
                                              const int* __restrict__ ridx) {
    const int h  = blockIdx.x;    // head 0..7
    const int p  = blockIdx.y;    // window 0..48
    const int nd = blockIdx.z;    // 0..15
    const int ndkv = ((nd & 7) == 7) ? nd : nd + 1;
    const int tid = threadIdx.x;

    __shared__ float Qs[64 * 36];    // stride 36: float4-aligned
    __shared__ float Ks[256 * 36];   // stride 36
    __shared__ float Vs[256 * 33];   // stride 33
    __shared__ int widx[4];

    if (tid < 4) widx[tid] = ridx[(nd * 49 + p) * 4 + tid];
    __syncthreads();

    const size_t qbase = ((size_t)(nd * 49 + p) * 64) * 256 + h * 32;
#pragma unroll
    for (int i = 0; i < 8; ++i) {              // 64x32 Q
        int idx = i * 256 + tid;
        int pix = idx >> 5, c = idx & 31;
        Qs[pix * 36 + c] = qa[qbase + (size_t)pix * 256 + c];
    }
#pragma unroll
    for (int i = 0; i < 32; ++i) {             // 256x32 K and V
        int idx = i * 256 + tid;
        int kk = idx >> 5, c = idx & 31;
        int s = kk >> 6, pix = kk & 63;
        size_t base = ((size_t)(ndkv * 49 + widx[s]) * 64 + pix) * 512 + h * 32 + c;
        Ks[kk * 36 + c] = kv_ws[base];
        Vs[kk * 33 + c] = kv_ws[base + 256];
    }
    __syncthreads();

    const int row  = tid >> 2;    // query pixel 0..63
    const int part = tid & 3;     // key partition (k = 4*kk + part)

    float4 qreg[8];
#pragma unroll
    for (int c4 = 0; c4 < 8; ++c4) {
        float4 v = *(const float4*)&Qs[row * 36 + c4 * 4];
        qreg[c4] = make_float4(v.x * SCALE, v.y * SCALE, v.z * SCALE, v.w * SCALE);
    }

    float s[64];
#pragma unroll
    for (int kk = 0; kk < 64; ++kk) {
        int k = 4 * kk + part;
        const float4* kp = (const float4*)&Ks[k * 36];
        float acc = 0.f;
#pragma unroll
        for (int c4 = 0; c4 < 8; ++c4) {
            float4 kv = kp[c4];
            acc += qreg[c4].x * kv.x + qreg[c4].y * kv.y
                 + qreg[c4].z * kv.z + qreg[c4].w * kv.w;
        }
        s[kk] = acc;
    }

    float mx = -INFINITY;
#pragma unroll
    for (int kk = 0; kk < 64; ++kk) mx = fmaxf(mx, s[kk]);
    mx = fmaxf(mx, __shfl_xor(mx, 1));
    mx = fmaxf(mx, __shfl_xor(mx, 2));
    float sum = 0.f;
#pragma unroll
    for (int kk = 0; kk < 64; ++kk) { s[kk] = __expf(s[kk] - mx); sum += s[kk]; }
    sum += __shfl_xor(sum, 1);
    sum += __shfl_xor(sum, 2);
    const float inv = 1.f / sum;

    float o[32] = {};
#pragma unroll
    for (int kk = 0; kk < 64; ++kk) {
        int k = 4 * kk + part;
        float pk = s[kk];
        const float* vp = &Vs[k * 33];
#pragma unroll
        for (int c = 0; c < 32; ++c) o[c] += pk * vp[c];
    }
#pragma unroll
    for (int c = 0; c < 32; ++c) {
        o[c] += __shfl_xor(o[c], 1);
        o[c] += __shfl_xor(o[c], 2);
    }

    __syncthreads();                 // Qs no longer needed; reuse for write staging
    if (part == 0) {
#pragma unroll
        for (int c = 0; c < 32; ++c) Qs[row * 36 + c] = o[c] * inv;
    }
    __syncthreads();
#pragma unroll
    for (int i = 0; i < 8; ++i) {
        int idx = i * 256 + tid;
        int pix = idx >> 5, c = idx & 31;
        qa[qbase + (size_t)pix * 256 + c] = Qs[pix * 36 + c];
    }
}

// ---------------------------------------------------------------------------
// K5: out = attn_out @ Wo + bo, scattered back to [nd][H][W][C] layout
// ---------------------------------------------------------------------------
__global__ __launch_bounds__(256) void k_oproj(const float* __restrict__ ao,
                                               const float* __restrict__ Wo,
                                               const float* __restrict__ bo,
                                               float* __restrict__ out) {
    __shared__ float As[16 * 68];
    __shared__ float Bs[16 * 64];
    const int tid = threadIdx.x;
    const int m0 = blockIdx.y * 64;
    const int n0 = blockIdx.x * 64;

    const int ar = tid >> 2;
    const int ak = (tid & 3) * 4;
    const float* aptr = ao + (size_t)(m0 + ar) * 256 + ak;

    const int bk = tid >> 4;
    const int bn = (tid & 15) * 4;
    const float* bptr = Wo + (size_t)bk * 256 + n0 + bn;

    const int ty = tid >> 4, tx = tid & 15;
    float acc[4][4] = {};

    for (int kt = 0; kt < 256; kt += 16) {
        float4 av = *(const float4*)(aptr + kt);
        float4 bv = *(const float4*)(bptr + (size_t)kt * 256);
        __syncthreads();
        As[(ak + 0) * 68 + ar] = av.x;
        As[(ak + 1) * 68 + ar] = av.y;
        As[(ak + 2) * 68 + ar] = av.z;
        As[(ak + 3) * 68 + ar] = av.w;
        *(float4*)&Bs[bk * 64 + bn] = bv;
        __syncthreads();
#pragma unroll
        for (int kk = 0; kk < 16; ++kk) {
            float4 a4 = *(const float4*)&As[kk * 68 + ty * 4];
            float4 b4 = *(const float4*)&Bs[kk * 64 + tx * 4];
            float a[4] = {a4.x, a4.y, a4.z, a4.w};
            float b[4] = {b4.x, b4.y, b4.z, b4.w};
#pragma unroll
            for (int ii = 0; ii < 4; ++ii)
#pragma unroll
                for (int jj = 0; jj < 4; ++jj) acc[ii][jj] += a[ii] * b[jj];
        }
    }
#pragma unroll
    for (int ii = 0; ii < 4; ++ii) {
        int t = m0 + ty * 4 + ii;
        int xr = token_to_xrow(t);
#pragma unroll
        for (int jj = 0; jj < 4; ++jj) {
            int col = n0 + tx * 4 + jj;
            out[(size_t)xr * 256 + col] = acc[ii][jj] + bo[col];
        }
    }
}

// ---------------------------------------------------------------------------
extern "C" void kernel_launch(void* const* d_in, const int* in_sizes, int n_in,
                              void* d_out, int out_size, void* d_ws, size_t ws_size,
                              hipStream_t stream) {
    const float* x    = (const float*)d_in[0];
    const float* Wqkv = (const float*)d_in[1];
    const float* bqkv = (const float*)d_in[2];
    const float* Wo   = (const float*)d_in[3];
    const float* bo   = (const float*)d_in[4];
    float* out = (float*)d_out;

    float* ws = (float*)d_ws;
    float* q_ws  = ws;                       // 50176*256 = 12,845,056 floats
    float* kv_ws = ws + 12845056;            // 50176*512 = 25,690,112 floats
    float* qwin  = ws + 12845056 + 25690112; // 16*49*256 = 200,704
    float* kwin  = qwin + 200704;            // 200,704
    int*   ridx  = (int*)(kwin + 200704);    // 16*49*4 ints

    k_qkv  <<<dim3(12, 784), 256, 0, stream>>>(x, Wqkv, bqkv, q_ws, kv_ws);
    k_means<<<784, 256, 0, stream>>>(q_ws, kv_ws, qwin, kwin);
    k_route<<<784, 64, 0, stream>>>(qwin, kwin, ridx);
    k_attn <<<dim3(8, 49, 16), 256, 0, stream>>>(q_ws, kv_ws, ridx);
    k_oproj<<<dim3(4, 784), 256, 0, stream>>>(q_ws, Wo, bo, out);
}

// Round 2
// 258.240 us; speedup vs baseline: 3.4504x; 3.4504x over previous
//
#include <hip/hip_runtime.h>
#include <math.h>

#define SCALE 0.0625f   // 256^-0.5

typedef __attribute__((ext_vector_type(8))) short bf16x8;
typedef __attribute__((ext_vector_type(4))) float f32x4;

// fp32 -> bf16 round-to-nearest-even
__device__ __forceinline__ ushort f2bf(float f) {
    unsigned u = __float_as_uint(f);
    return (ushort)((u + 0x7FFFu + ((u >> 16) & 1u)) >> 16);
}

// token t (window order: [nd][p][pix]) -> row in x/out layout [nd][H][W]
__device__ __forceinline__ int token_to_xrow(int t) {
    int nd  = t / 3136;          // 49*64
    int r   = t % 3136;
    int p   = r >> 6;            // window 0..48
    int pix = r & 63;            // pixel 0..63
    int j = p / 7, i = p % 7;
    int hh = pix >> 3, ww = pix & 7;
    return nd * 3136 + (j * 8 + hh) * 56 + (i * 8 + ww);
}

// ---------------------------------------------------------------------------
// Casts: x -> window-gathered bf16 xg[t][256]; W -> transposed bf16
// ---------------------------------------------------------------------------
__global__ __launch_bounds__(256) void k_cast_x(const float* __restrict__ x,
                                                ushort* __restrict__ xg) {
    int gid = blockIdx.x * 256 + threadIdx.x;   // 50176*64 float4-slots
    int t = gid >> 6, c = (gid & 63) * 4;
    float4 v = *(const float4*)&x[(size_t)token_to_xrow(t) * 256 + c];
    ushort4 o;
    o.x = f2bf(v.x); o.y = f2bf(v.y); o.z = f2bf(v.z); o.w = f2bf(v.w);
    *(ushort4*)&xg[(size_t)t * 256 + c] = o;
}

__global__ __launch_bounds__(256) void k_cast_w(const float* __restrict__ Wqkv,
                                                const float* __restrict__ Wo,
                                                ushort* __restrict__ Wqkvt,
                                                ushort* __restrict__ Wot) {
    int b = blockIdx.x, tid = threadIdx.x;
    if (b < 768) Wqkvt[b * 256 + tid] = f2bf(Wqkv[(size_t)tid * 768 + b]);
    else { int n = b - 768; Wot[n * 256 + tid] = f2bf(Wo[(size_t)tid * 256 + n]); }
}

// ---------------------------------------------------------------------------
// Routing path, pure fp32 (decoupled from bf16): window means of x, then
// (mean x) @ Wqkv[:, :512] + b  ->  qwin/kwin, then top-4.
// ---------------------------------------------------------------------------
__global__ __launch_bounds__(256) void k_xmean(const float* __restrict__ x,
                                               float* __restrict__ xmean) {
    int b = blockIdx.x;               // nd*49 + p
    int nd = b / 49, p = b % 49;
    int j = p / 7, i = p % 7;
    const float* xb = x + ((size_t)nd * 3136 + (j * 8) * 56 + i * 8) * 256 + threadIdx.x;
    float s = 0.f;
#pragma unroll
    for (int hh = 0; hh < 8; ++hh)
#pragma unroll
        for (int ww = 0; ww < 8; ++ww) s += xb[(size_t)(hh * 56 + ww) * 256];
    xmean[(size_t)b * 256 + threadIdx.x] = s * (1.f / 64.f);
}

__global__ __launch_bounds__(256) void k_winproj(const float* __restrict__ xmean,
                                                 const float* __restrict__ Wqkv,
                                                 const float* __restrict__ bqkv,
                                                 float* __restrict__ qwin,
                                                 float* __restrict__ kwin) {
    __shared__ float As[16 * 68];
    __shared__ float Bs[16 * 64];
    const int tid = threadIdx.x;
    const int m0 = blockIdx.y * 64;   // window-row tile (0..832)
    const int n0 = blockIdx.x * 64;   // col tile (0..511)

    const int ar = tid >> 2;
    const int ak = (tid & 3) * 4;
    const int arow = (m0 + ar < 784) ? (m0 + ar) : 783;
    const float* aptr = xmean + (size_t)arow * 256 + ak;

    const int bk = tid >> 4;
    const int bn = (tid & 15) * 4;
    const float* bptr = Wqkv + (size_t)bk * 768 + n0 + bn;

    const int ty = tid >> 4, tx = tid & 15;
    float acc[4][4] = {};

    for (int kt = 0; kt < 256; kt += 16) {
        float4 av = *(const float4*)(aptr + kt);
        float4 bv = *(const float4*)(bptr + (size_t)kt * 768);
        __syncthreads();
        As[(ak + 0) * 68 + ar] = av.x;
        As[(ak + 1) * 68 + ar] = av.y;
        As[(ak + 2) * 68 + ar] = av.z;
        As[(ak + 3) * 68 + ar] = av.w;
        *(float4*)&Bs[bk * 64 + bn] = bv;
        __syncthreads();
#pragma unroll
        for (int kk = 0; kk < 16; ++kk) {
            float4 a4 = *(const float4*)&As[kk * 68 + ty * 4];
            float4 b4 = *(const float4*)&Bs[kk * 64 + tx * 4];
            float a[4] = {a4.x, a4.y, a4.z, a4.w};
            float b[4] = {b4.x, b4.y, b4.z, b4.w};
#pragma unroll
            for (int ii = 0; ii < 4; ++ii)
#pragma unroll
                for (int jj = 0; jj < 4; ++jj) acc[ii][jj] += a[ii] * b[jj];
        }
    }
#pragma unroll
    for (int ii = 0; ii < 4; ++ii) {
        int t = m0 + ty * 4 + ii;
        if (t >= 784) continue;
#pragma unroll
        for (int jj = 0; jj < 4; ++jj) {
            int col = n0 + tx * 4 + jj;
            float v = acc[ii][jj] + bqkv[col];
            if (col < 256) qwin[(size_t)t * 256 + col] = v;
            else           kwin[(size_t)t * 256 + (col - 256)] = v;
        }
    }
}

__global__ __launch_bounds__(64) void k_route(const float* __restrict__ qwin,
                                              const float* __restrict__ kwin,
                                              int* __restrict__ ridx) {
    const int b = blockIdx.x;                 // nd*49 + p
    const int nd = b / 49;
    const int ndkv = ((nd & 7) == 7) ? nd : nd + 1;
    const int t = threadIdx.x;
    __shared__ float qs[256];
    for (int i = t; i < 256; i += 64) qs[i] = qwin[b * 256 + i];
    __syncthreads();
    float logit = -INFINITY;
    if (t < 49) {
        const float* kr = kwin + ((size_t)ndkv * 49 + t) * 256;
        float s = 0.f;
        for (int c = 0; c < 256; ++c) s += qs[c] * kr[c];
        logit = s;
    }
    for (int sel = 0; sel < 4; ++sel) {
        float v = logit;
        int ix = t;
        for (int off = 32; off > 0; off >>= 1) {
            float ov = __shfl_xor(v, off);
            int   oi = __shfl_xor(ix, off);
            if (ov > v || (ov == v && oi < ix)) { v = ov; ix = oi; }
        }
        if (t == 0) ridx[b * 4 + sel] = ix;
        if (t == ix) logit = -INFINITY;
    }
}

// ---------------------------------------------------------------------------
// bf16 MFMA GEMM, 128x128 tile, BK=32, reg-staged with prefetch.
// A[M][256] bf16 row-major, Bt[N][256] bf16 row-major (B pre-transposed).
// ---------------------------------------------------------------------------
__global__ __launch_bounds__(256) void k_gemm_qkv(const ushort* __restrict__ A,
                                                  const ushort* __restrict__ Bt,
                                                  const float* __restrict__ bqkv,
                                                  ushort* __restrict__ q,
                                                  ushort* __restrict__ kv) {
    __shared__ ushort As[128 * 32];
    __shared__ ushort Bs[128 * 32];
    const int tid = threadIdx.x;
    const int wv = tid >> 6, ln = tid & 63;
    const int lane15 = ln & 15, quad = ln >> 4;
    const int m0 = blockIdx.y * 128, n0 = blockIdx.x * 128;

    // staging slots: slot = p*256 + tid; row = slot>>2; chunk = slot&3
    const int row0 = tid >> 2, ck = tid & 3;

    f32x4 acc[4][4];
#pragma unroll
    for (int i = 0; i < 4; ++i)
#pragma unroll
        for (int j = 0; j < 4; ++j) acc[i][j] = (f32x4){0.f, 0.f, 0.f, 0.f};

    bf16x8 avA[2], avB[2];
#pragma unroll
    for (int p = 0; p < 2; ++p) {
        avA[p] = *(const bf16x8*)(A  + (size_t)(m0 + p * 64 + row0) * 256 + ck * 8);
        avB[p] = *(const bf16x8*)(Bt + (size_t)(n0 + p * 64 + row0) * 256 + ck * 8);
    }

    const int mb = (wv >> 1) * 64, nb = (wv & 1) * 64;

    for (int kt = 0; kt < 8; ++kt) {
        __syncthreads();
#pragma unroll
        for (int p = 0; p < 2; ++p) {
            *(bf16x8*)&As[(p * 256 + tid) * 8] = avA[p];
            *(bf16x8*)&Bs[(p * 256 + tid) * 8] = avB[p];
        }
        if (kt < 7) {
#pragma unroll
            for (int p = 0; p < 2; ++p) {
                avA[p] = *(const bf16x8*)(A  + (size_t)(m0 + p * 64 + row0) * 256 + (kt + 1) * 32 + ck * 8);
                avB[p] = *(const bf16x8*)(Bt + (size_t)(n0 + p * 64 + row0) * 256 + (kt + 1) * 32 + ck * 8);
            }
        }
        __syncthreads();
        bf16x8 aF[4], bF[4];
#pragma unroll
        for (int mt = 0; mt < 4; ++mt)
            aF[mt] = *(const bf16x8*)&As[(mb + mt * 16 + lane15) * 32 + quad * 8];
#pragma unroll
        for (int nt = 0; nt < 4; ++nt)
            bF[nt] = *(const bf16x8*)&Bs[(nb + nt * 16 + lane15) * 32 + quad * 8];
#pragma unroll
        for (int mt = 0; mt < 4; ++mt)
#pragma unroll
            for (int nt = 0; nt < 4; ++nt)
                acc[mt][nt] = __builtin_amdgcn_mfma_f32_16x16x32_bf16(aF[mt], bF[nt], acc[mt][nt], 0, 0, 0);
    }

#pragma unroll
    for (int mt = 0; mt < 4; ++mt) {
#pragma unroll
        for (int nt = 0; nt < 4; ++nt) {
            int col = n0 + nb + nt * 16 + lane15;
            float bias = bqkv[col];
#pragma unroll
            for (int r = 0; r < 4; ++r) {
                int t = m0 + mb + mt * 16 + quad * 4 + r;
                ushort b = f2bf(acc[mt][nt][r] + bias);
                if (col < 256) q[(size_t)t * 256 + col] = b;
                else           kv[(size_t)t * 512 + (col - 256)] = b;
            }
        }
    }
}

__global__ __launch_bounds__(256) void k_gemm_o(const ushort* __restrict__ A,
                                                const ushort* __restrict__ Bt,
                                                const float* __restrict__ bo,
                                                float* __restrict__ out) {
    __shared__ ushort As[128 * 32];
    __shared__ ushort Bs[128 * 32];
    const int tid = threadIdx.x;
    const int wv = tid >> 6, ln = tid & 63;
    const int lane15 = ln & 15, quad = ln >> 4;
    const int m0 = blockIdx.y * 128, n0 = blockIdx.x * 128;
    const int row0 = tid >> 2, ck = tid & 3;

    f32x4 acc[4][4];
#pragma unroll
    for (int i = 0; i < 4; ++i)
#pragma unroll
        for (int j = 0; j < 4; ++j) acc[i][j] = (f32x4){0.f, 0.f, 0.f, 0.f};

    bf16x8 avA[2], avB[2];
#pragma unroll
    for (int p = 0; p < 2; ++p) {
        avA[p] = *(const bf16x8*)(A  + (size_t)(m0 + p * 64 + row0) * 256 + ck * 8);
        avB[p] = *(const bf16x8*)(Bt + (size_t)(n0 + p * 64 + row0) * 256 + ck * 8);
    }
    const int mb = (wv >> 1) * 64, nb = (wv & 1) * 64;

    for (int kt = 0; kt < 8; ++kt) {
        __syncthreads();
#pragma unroll
        for (int p = 0; p < 2; ++p) {
            *(bf16x8*)&As[(p * 256 + tid) * 8] = avA[p];
            *(bf16x8*)&Bs[(p * 256 + tid) * 8] = avB[p];
        }
        if (kt < 7) {
#pragma unroll
            for (int p = 0; p < 2; ++p) {
                avA[p] = *(const bf16x8*)(A  + (size_t)(m0 + p * 64 + row0) * 256 + (kt + 1) * 32 + ck * 8);
                avB[p] = *(const bf16x8*)(Bt + (size_t)(n0 + p * 64 + row0) * 256 + (kt + 1) * 32 + ck * 8);
            }
        }
        __syncthreads();
        bf16x8 aF[4], bF[4];
#pragma unroll
        for (int mt = 0; mt < 4; ++mt)
            aF[mt] = *(const bf16x8*)&As[(mb + mt * 16 + lane15) * 32 + quad * 8];
#pragma unroll
        for (int nt = 0; nt < 4; ++nt)
            bF[nt] = *(const bf16x8*)&Bs[(nb + nt * 16 + lane15) * 32 + quad * 8];
#pragma unroll
        for (int mt = 0; mt < 4; ++mt)
#pragma unroll
            for (int nt = 0; nt < 4; ++nt)
                acc[mt][nt] = __builtin_amdgcn_mfma_f32_16x16x32_bf16(aF[mt], bF[nt], acc[mt][nt], 0, 0, 0);
    }

#pragma unroll
    for (int mt = 0; mt < 4; ++mt) {
#pragma unroll
        for (int nt = 0; nt < 4; ++nt) {
            int col = n0 + nb + nt * 16 + lane15;
            float bias = bo[col];
#pragma unroll
            for (int r = 0; r < 4; ++r) {
                int t = m0 + mb + mt * 16 + quad * 4 + r;
                int xr = token_to_xrow(t);
                out[(size_t)xr * 256 + col] = acc[mt][nt][r] + bias;
            }
        }
    }
}

// ---------------------------------------------------------------------------
// Attention per (head, window, nd): S^T = K·Q^T via MFMA (col = q-row), softmax
// mostly in-lane, P through LDS (b64 packed writes / b128 A-frag reads), PV via
// MFMA with transposed-V LDS. Output written in-place over q (bf16).
// ---------------------------------------------------------------------------
__global__ __launch_bounds__(256, 3) void k_attn(ushort* qbuf,
                                                 const ushort* __restrict__ kvbuf,
                                                 const int* __restrict__ ridx) {
    const int h = blockIdx.x, p = blockIdx.y, nd = blockIdx.z;
    const int ndkv = ((nd & 7) == 7) ? nd : nd + 1;
    const int tid = threadIdx.x;
    const int wv = tid >> 6, ln = tid & 63;
    const int lane15 = ln & 15, quad = ln >> 4;

    __shared__ ushort Ks[256 * 32];   // [key][ch]    16 KB
    __shared__ ushort Vt[32 * 272];   // [ch][key]+pad 17 KB
    __shared__ ushort Ps[64 * 72];    // [qrow][64key chunk]+pad 9 KB

    const int rb = (nd * 49 + p) * 4;
    int wid[4];
#pragma unroll
    for (int i = 0; i < 4; ++i) wid[i] = ridx[rb + i];

    const size_t kvband = (size_t)ndkv * 49;

    // ---- stage K: [key][32ch] bf16, coalesced b128 ----
    {
        int pix = tid >> 2, ck = tid & 3;
#pragma unroll
        for (int i = 0; i < 4; ++i) {
            size_t trow = (kvband + wid[i]) * 64 + pix;
            bf16x8 v = *(const bf16x8*)(kvbuf + trow * 512 + h * 32 + ck * 8);
            *(bf16x8*)&Ks[(i * 64 + pix) * 32 + ck * 8] = v;
        }
    }
    // ---- stage V transposed: Vt[ch][key] ----
    {
        int key_l = (tid & 31) * 2;       // 0..62 within window
        int ch0 = (tid >> 5) * 4;         // 0..28
#pragma unroll
        for (int i = 0; i < 4; ++i) {
            size_t trow = (kvband + wid[i]) * 64;
            const ushort* g0 = kvbuf + (trow + key_l) * 512 + 256 + h * 32 + ch0;
            const ushort* g1 = g0 + 512;
            ushort4 a = *(const ushort4*)g0;
            ushort4 b = *(const ushort4*)g1;
            int kg = i * 64 + key_l;
            *(unsigned*)&Vt[(ch0 + 0) * 272 + kg] = (unsigned)a.x | ((unsigned)b.x << 16);
            *(unsigned*)&Vt[(ch0 + 1) * 272 + kg] = (unsigned)a.y | ((unsigned)b.y << 16);
            *(unsigned*)&Vt[(ch0 + 2) * 272 + kg] = (unsigned)a.z | ((unsigned)b.z << 16);
            *(unsigned*)&Vt[(ch0 + 3) * 272 + kg] = (unsigned)a.w | ((unsigned)b.w << 16);
        }
    }

    // ---- Q B-frag from global (wave's own 16 q-rows) ----
    const size_t qrow0 = (size_t)(nd * 49 + p) * 64;
    bf16x8 bQ = *(const bf16x8*)(qbuf + (qrow0 + wv * 16 + lane15) * 256 + h * 32 + quad * 8);

    __syncthreads();

    // ---- S^T = K · Q^T : 16 key-tiles of 16, K-dim = 32 (one mfma each) ----
    f32x4 st[16];
#pragma unroll
    for (int t = 0; t < 16; ++t) {
        bf16x8 aK = *(const bf16x8*)&Ks[(t * 16 + lane15) * 32 + quad * 8];
        st[t] = __builtin_amdgcn_mfma_f32_16x16x32_bf16(aK, bQ, (f32x4){0.f, 0.f, 0.f, 0.f}, 0, 0, 0);
    }

    // ---- softmax over keys (in-lane 64 values + quad all-reduce) ----
    float mx = -1e30f;
#pragma unroll
    for (int t = 0; t < 16; ++t)
#pragma unroll
        for (int r = 0; r < 4; ++r) mx = fmaxf(mx, st[t][r]);
    mx = fmaxf(mx, __shfl_xor(mx, 16));
    mx = fmaxf(mx, __shfl_xor(mx, 32));
    float sum = 0.f;
#pragma unroll
    for (int t = 0; t < 16; ++t)
#pragma unroll
        for (int r = 0; r < 4; ++r) {
            float e = __expf((st[t][r] - mx) * SCALE);
            st[t][r] = e;
            sum += e;
        }
    sum += __shfl_xor(sum, 16);
    sum += __shfl_xor(sum, 32);
    const float inv = 1.f / sum;

    // ---- PV in 4 key-chunks of 64, P through wave-private LDS ----
    f32x4 oacc[2] = {{0.f, 0.f, 0.f, 0.f}, {0.f, 0.f, 0.f, 0.f}};
    const int prow = (wv * 16 + lane15) * 72;
#pragma unroll
    for (int cc = 0; cc < 4; ++cc) {
#pragma unroll
        for (int tt = 0; tt < 4; ++tt) {
            int t = cc * 4 + tt;
            unsigned lo = (unsigned)f2bf(st[t][0] * inv) | ((unsigned)f2bf(st[t][1] * inv) << 16);
            unsigned hi = (unsigned)f2bf(st[t][2] * inv) | ((unsigned)f2bf(st[t][3] * inv) << 16);
            uint2 pk; pk.x = lo; pk.y = hi;
            *(uint2*)&Ps[prow + tt * 16 + quad * 4] = pk;   // keys tt*16+4q..+3
        }
#pragma unroll
        for (int kt = 0; kt < 2; ++kt) {
            bf16x8 aP = *(const bf16x8*)&Ps[prow + kt * 32 + quad * 8];
#pragma unroll
            for (int nt = 0; nt < 2; ++nt) {
                bf16x8 bV = *(const bf16x8*)&Vt[(nt * 16 + lane15) * 272 + cc * 64 + kt * 32 + quad * 8];
                oacc[nt] = __builtin_amdgcn_mfma_f32_16x16x32_bf16(aP, bV, oacc[nt], 0, 0, 0);
            }
        }
    }

    // ---- store (in-place over qbuf; wave owns exactly its 16 rows) ----
#pragma unroll
    for (int nt = 0; nt < 2; ++nt)
#pragma unroll
        for (int r = 0; r < 4; ++r) {
            int row = wv * 16 + quad * 4 + r;
            qbuf[(qrow0 + row) * 256 + h * 32 + nt * 16 + lane15] = f2bf(oacc[nt][r]);
        }
}

// ---------------------------------------------------------------------------
extern "C" void kernel_launch(void* const* d_in, const int* in_sizes, int n_in,
                              void* d_out, int out_size, void* d_ws, size_t ws_size,
                              hipStream_t stream) {
    const float* x    = (const float*)d_in[0];
    const float* Wqkv = (const float*)d_in[1];
    const float* bqkv = (const float*)d_in[2];
    const float* Wo   = (const float*)d_in[3];
    const float* bo   = (const float*)d_in[4];
    float* out = (float*)d_out;

    char* ws = (char*)d_ws;
    ushort* xg    = (ushort*)ws;                    ws += (size_t)50176 * 256 * 2;  // 25.7 MB
    ushort* q     = (ushort*)ws;                    ws += (size_t)50176 * 256 * 2;  // 25.7 MB
    ushort* kv    = (ushort*)ws;                    ws += (size_t)50176 * 512 * 2;  // 51.4 MB
    ushort* Wqkvt = (ushort*)ws;                    ws += (size_t)768 * 256 * 2;
    ushort* Wot   = (ushort*)ws;                    ws += (size_t)256 * 256 * 2;
    float*  xmean = (float*)ws;                     ws += (size_t)784 * 256 * 4;
    float*  qwin  = (float*)ws;                     ws += (size_t)784 * 256 * 4;
    float*  kwin  = (float*)ws;                     ws += (size_t)784 * 256 * 4;
    int*    ridx  = (int*)ws;

    k_cast_w  <<<1024, 256, 0, stream>>>(Wqkv, Wo, Wqkvt, Wot);
    k_cast_x  <<<12544, 256, 0, stream>>>(x, xg);
    k_xmean   <<<784, 256, 0, stream>>>(x, xmean);
    k_winproj <<<dim3(8, 13), 256, 0, stream>>>(xmean, Wqkv, bqkv, qwin, kwin);
    k_route   <<<784, 64, 0, stream>>>(qwin, kwin, ridx);
    k_gemm_qkv<<<dim3(6, 392), 256, 0, stream>>>(xg, Wqkvt, bqkv, q, kv);
    k_attn    <<<dim3(8, 49, 16), 256, 0, stream>>>(q, kv, ridx);
    k_gemm_o  <<<dim3(2, 392), 256, 0, stream>>>(q, Wot, bo, out);
}

// Round 4
// 257.551 us; speedup vs baseline: 3.4597x; 1.0027x over previous
//
#include <hip/hip_runtime.h>
#include <hip/hip_bf16.h>
#include <math.h>

// attention scale folded with log2(e) for exp2-based softmax:
// q_attn = q * (256^-0.5 * log2(e))
#define QSC 0.09016844f

typedef __attribute__((ext_vector_type(8))) short bf16x8;
typedef __attribute__((ext_vector_type(4))) float f32x4;

// fp32 -> bf16 round-to-nearest-even
__device__ __forceinline__ ushort f2bf(float f) {
    unsigned u = __float_as_uint(f);
    return (ushort)((u + 0x7FFFu + ((u >> 16) & 1u)) >> 16);
}

__device__ __forceinline__ unsigned pk2bf(float a, float b) {
    __hip_bfloat162 h = __float22bfloat162_rn(make_float2(a, b));
    return *(unsigned*)&h;
}

// async global->LDS, 16B per lane. LDS dest must be wave-uniform base + lane*16.
__device__ __forceinline__ void gl_lds16(const ushort* g, ushort* l) {
    __builtin_amdgcn_global_load_lds(
        (const __attribute__((address_space(1))) unsigned int*)g,
        (__attribute__((address_space(3))) unsigned int*)l, 16, 0, 0);
}

// token t (window order: [nd][p][pix]) -> row in x/out layout [nd][H][W]
__device__ __forceinline__ int token_to_xrow(int t) {
    int nd  = t / 3136;          // 49*64
    int r   = t % 3136;
    int p   = r >> 6;            // window 0..48
    int pix = r & 63;            // pixel 0..63
    int j = p / 7, i = p % 7;
    int hh = pix >> 3, ww = pix & 7;
    return nd * 3136 + (j * 8 + hh) * 56 + (i * 8 + ww);
}

// ---------------------------------------------------------------------------
// Casts: x -> window-gathered bf16 xg[t][256]; W -> transposed bf16
// ---------------------------------------------------------------------------
__global__ __launch_bounds__(256) void k_cast_x(const float* __restrict__ x,
                                                ushort* __restrict__ xg) {
    int gid = blockIdx.x * 256 + threadIdx.x;   // 50176*64 float4-slots
    int t = gid >> 6, c = (gid & 63) * 4;
    float4 v = *(const float4*)&x[(size_t)token_to_xrow(t) * 256 + c];
    ushort4 o;
    o.x = f2bf(v.x); o.y = f2bf(v.y); o.z = f2bf(v.z); o.w = f2bf(v.w);
    *(ushort4*)&xg[(size_t)t * 256 + c] = o;
}

__global__ __launch_bounds__(256) void k_cast_w(const float* __restrict__ Wqkv,
                                                const float* __restrict__ Wo,
                                                ushort* __restrict__ Wqkvt,
                                                ushort* __restrict__ Wot) {
    int b = blockIdx.x, tid = threadIdx.x;
    if (b < 768) Wqkvt[b * 256 + tid] = f2bf(Wqkv[(size_t)tid * 768 + b]);
    else { int n = b - 768; Wot[n * 256 + tid] = f2bf(Wo[(size_t)tid * 256 + n]); }
}

// ---------------------------------------------------------------------------
// Routing path, pure fp32 (decoupled from bf16 numerics).
// ---------------------------------------------------------------------------
__global__ __launch_bounds__(256) void k_xmean(const float* __restrict__ x,
                                               float* __restrict__ xmean) {
    int b = blockIdx.x;               // nd*49 + p
    int nd = b / 49, p = b % 49;
    int j = p / 7, i = p % 7;
    const float* xb = x + ((size_t)nd * 3136 + (j * 8) * 56 + i * 8) * 256 + threadIdx.x;
    float s = 0.f;
#pragma unroll
    for (int hh = 0; hh < 8; ++hh)
#pragma unroll
        for (int ww = 0; ww < 8; ++ww) s += xb[(size_t)(hh * 56 + ww) * 256];
    xmean[(size_t)b * 256 + threadIdx.x] = s * (1.f / 64.f);
}

__global__ __launch_bounds__(256) void k_winproj(const float* __restrict__ xmean,
                                                 const float* __restrict__ Wqkv,
                                                 const float* __restrict__ bqkv,
                                                 float* __restrict__ qwin,
                                                 float* __restrict__ kwin) {
    __shared__ float As[16 * 68];
    __shared__ float Bs[16 * 64];
    const int tid = threadIdx.x;
    const int m0 = blockIdx.y * 64;
    const int n0 = blockIdx.x * 64;

    const int ar = tid >> 2;
    const int ak = (tid & 3) * 4;
    const int arow = (m0 + ar < 784) ? (m0 + ar) : 783;
    const float* aptr = xmean + (size_t)arow * 256 + ak;

    const int bk = tid >> 4;
    const int bn = (tid & 15) * 4;
    const float* bptr = Wqkv + (size_t)bk * 768 + n0 + bn;

    const int ty = tid >> 4, tx = tid & 15;
    float acc[4][4] = {};

    for (int kt = 0; kt < 256; kt += 16) {
        float4 av = *(const float4*)(aptr + kt);
        float4 bv = *(const float4*)(bptr + (size_t)kt * 768);
        __syncthreads();
        As[(ak + 0) * 68 + ar] = av.x;
        As[(ak + 1) * 68 + ar] = av.y;
        As[(ak + 2) * 68 + ar] = av.z;
        As[(ak + 3) * 68 + ar] = av.w;
        *(float4*)&Bs[bk * 64 + bn] = bv;
        __syncthreads();
#pragma unroll
        for (int kk = 0; kk < 16; ++kk) {
            float4 a4 = *(const float4*)&As[kk * 68 + ty * 4];
            float4 b4 = *(const float4*)&Bs[kk * 64 + tx * 4];
            float a[4] = {a4.x, a4.y, a4.z, a4.w};
            float b[4] = {b4.x, b4.y, b4.z, b4.w};
#pragma unroll
            for (int ii = 0; ii < 4; ++ii)
#pragma unroll
                for (int jj = 0; jj < 4; ++jj) acc[ii][jj] += a[ii] * b[jj];
        }
    }
#pragma unroll
    for (int ii = 0; ii < 4; ++ii) {
        int t = m0 + ty * 4 + ii;
        if (t >= 784) continue;
#pragma unroll
        for (int jj = 0; jj < 4; ++jj) {
            int col = n0 + tx * 4 + jj;
            float v = acc[ii][jj] + bqkv[col];
            if (col < 256) qwin[(size_t)t * 256 + col] = v;
            else           kwin[(size_t)t * 256 + (col - 256)] = v;
        }
    }
}

__global__ __launch_bounds__(64) void k_route(const float* __restrict__ qwin,
                                              const float* __restrict__ kwin,
                                              int* __restrict__ ridx) {
    const int b = blockIdx.x;                 // nd*49 + p
    const int nd = b / 49;
    const int ndkv = ((nd & 7) == 7) ? nd : nd + 1;
    const int t = threadIdx.x;
    __shared__ float qs[256];
    for (int i = t; i < 256; i += 64) qs[i] = qwin[b * 256 + i];
    __syncthreads();
    float logit = -INFINITY;
    if (t < 49) {
        const float* kr = kwin + ((size_t)ndkv * 49 + t) * 256;
        float s = 0.f;
        for (int c = 0; c < 256; ++c) s += qs[c] * kr[c];
        logit = s;
    }
    for (int sel = 0; sel < 4; ++sel) {
        float v = logit;
        int ix = t;
        for (int off = 32; off > 0; off >>= 1) {
            float ov = __shfl_xor(v, off);
            int   oi = __shfl_xor(ix, off);
            if (ov > v || (ov == v && oi < ix)) { v = ov; ix = oi; }
        }
        if (t == 0) ridx[b * 4 + sel] = ix;
        if (t == ix) logit = -INFINITY;
    }
}

// ---------------------------------------------------------------------------
// bf16 MFMA GEMM, 128x128 tile, BK=32, m97-style direct-to-LDS staging.
// A[M][256], Bt[N][256] bf16 row-major. q gets the folded attention scale.
// ---------------------------------------------------------------------------
__global__ __launch_bounds__(256) void k_gemm_qkv(const ushort* __restrict__ A,
                                                  const ushort* __restrict__ Bt,
                                                  const float* __restrict__ bqkv,
                                                  ushort* __restrict__ q,
                                                  ushort* __restrict__ kv) {
    __shared__ ushort As[128 * 32];
    __shared__ ushort Bs[128 * 32];
    const int tid = threadIdx.x;
    const int wv = tid >> 6, ln = tid & 63;
    const int lane15 = ln & 15, quad = ln >> 4;
    const int m0 = blockIdx.y * 128, n0 = blockIdx.x * 128;
    const int row0 = tid >> 2, ck = tid & 3;

    const ushort* gA[2]; const ushort* gB[2];
    ushort* lA[2]; ushort* lB[2];
#pragma unroll
    for (int p = 0; p < 2; ++p) {
        gA[p] = A  + (size_t)(m0 + p * 64 + row0) * 256 + ck * 8;
        gB[p] = Bt + (size_t)(n0 + p * 64 + row0) * 256 + ck * 8;
        lA[p] = &As[(p * 256 + tid) * 8];
        lB[p] = &Bs[(p * 256 + tid) * 8];
    }

    f32x4 acc[4][4];
#pragma unroll
    for (int i = 0; i < 4; ++i)
#pragma unroll
        for (int j = 0; j < 4; ++j) acc[i][j] = (f32x4){0.f, 0.f, 0.f, 0.f};

    const int mb = (wv >> 1) * 64, nb = (wv & 1) * 64;

    for (int kt = 0; kt < 8; ++kt) {
        __syncthreads();
#pragma unroll
        for (int p = 0; p < 2; ++p) {
            gl_lds16(gA[p] + kt * 32, lA[p]);
            gl_lds16(gB[p] + kt * 32, lB[p]);
        }
        __syncthreads();
        bf16x8 aF[4], bF[4];
#pragma unroll
        for (int mt = 0; mt < 4; ++mt)
            aF[mt] = *(const bf16x8*)&As[(mb + mt * 16 + lane15) * 32 + quad * 8];
#pragma unroll
        for (int nt = 0; nt < 4; ++nt)
            bF[nt] = *(const bf16x8*)&Bs[(nb + nt * 16 + lane15) * 32 + quad * 8];
#pragma unroll
        for (int mt = 0; mt < 4; ++mt)
#pragma unroll
            for (int nt = 0; nt < 4; ++nt)
                acc[mt][nt] = __builtin_amdgcn_mfma_f32_16x16x32_bf16(aF[mt], bF[nt], acc[mt][nt], 0, 0, 0);
    }

#pragma unroll
    for (int mt = 0; mt < 4; ++mt) {
#pragma unroll
        for (int nt = 0; nt < 4; ++nt) {
            int col = n0 + nb + nt * 16 + lane15;
            float bias = bqkv[col];
#pragma unroll
            for (int r = 0; r < 4; ++r) {
                int t = m0 + mb + mt * 16 + quad * 4 + r;
                float v = acc[mt][nt][r] + bias;
                if (col < 256) q[(size_t)t * 256 + col] = f2bf(v * QSC);
                else           kv[(size_t)t * 512 + (col - 256)] = f2bf(v);
            }
        }
    }
}

__global__ __launch_bounds__(256) void k_gemm_o(const ushort* __restrict__ A,
                                                const ushort* __restrict__ Bt,
                                                const float* __restrict__ bo,
                                                float* __restrict__ out) {
    __shared__ ushort As[128 * 32];
    __shared__ ushort Bs[128 * 32];
    const int tid = threadIdx.x;
    const int wv = tid >> 6, ln = tid & 63;
    const int lane15 = ln & 15, quad = ln >> 4;
    const int m0 = blockIdx.y * 128, n0 = blockIdx.x * 128;
    const int row0 = tid >> 2, ck = tid & 3;

    const ushort* gA[2]; const ushort* gB[2];
    ushort* lA[2]; ushort* lB[2];
#pragma unroll
    for (int p = 0; p < 2; ++p) {
        gA[p] = A  + (size_t)(m0 + p * 64 + row0) * 256 + ck * 8;
        gB[p] = Bt + (size_t)(n0 + p * 64 + row0) * 256 + ck * 8;
        lA[p] = &As[(p * 256 + tid) * 8];
        lB[p] = &Bs[(p * 256 + tid) * 8];
    }

    f32x4 acc[4][4];
#pragma unroll
    for (int i = 0; i < 4; ++i)
#pragma unroll
        for (int j = 0; j < 4; ++j) acc[i][j] = (f32x4){0.f, 0.f, 0.f, 0.f};

    const int mb = (wv >> 1) * 64, nb = (wv & 1) * 64;

    for (int kt = 0; kt < 8; ++kt) {
        __syncthreads();
#pragma unroll
        for (int p = 0; p < 2; ++p) {
            gl_lds16(gA[p] + kt * 32, lA[p]);
            gl_lds16(gB[p] + kt * 32, lB[p]);
        }
        __syncthreads();
        bf16x8 aF[4], bF[4];
#pragma unroll
        for (int mt = 0; mt < 4; ++mt)
            aF[mt] = *(const bf16x8*)&As[(mb + mt * 16 + lane15) * 32 + quad * 8];
#pragma unroll
        for (int nt = 0; nt < 4; ++nt)
            bF[nt] = *(const bf16x8*)&Bs[(nb + nt * 16 + lane15) * 32 + quad * 8];
#pragma unroll
        for (int mt = 0; mt < 4; ++mt)
#pragma unroll
            for (int nt = 0; nt < 4; ++nt)
                acc[mt][nt] = __builtin_amdgcn_mfma_f32_16x16x32_bf16(aF[mt], bF[nt], acc[mt][nt], 0, 0, 0);
    }

#pragma unroll
    for (int mt = 0; mt < 4; ++mt) {
#pragma unroll
        for (int nt = 0; nt < 4; ++nt) {
            int col = n0 + nb + nt * 16 + lane15;
            float bias = bo[col];
#pragma unroll
            for (int r = 0; r < 4; ++r) {
                int t = m0 + mb + mt * 16 + quad * 4 + r;
                int xr = token_to_xrow(t);
                out[(size_t)xr * 256 + col] = acc[mt][nt][r] + bias;
            }
        }
    }
}

// ---------------------------------------------------------------------------
// Attention per (head, window, nd). q already carries SCALE*log2e:
// softmax = exp2(score), normalization deferred to the output.
// LDS strides: Ks 40 (2-way banks), Vt 264 (2-way), Ps 72 (2-way).
// ---------------------------------------------------------------------------
__global__ __launch_bounds__(256, 3) void k_attn(ushort* qbuf,
                                                 const ushort* __restrict__ kvbuf,
                                                 const int* __restrict__ ridx) {
    const int h = blockIdx.x, p = blockIdx.y, nd = blockIdx.z;
    const int ndkv = ((nd & 7) == 7) ? nd : nd + 1;
    const int tid = threadIdx.x;
    const int wv = tid >> 6, ln = tid & 63;
    const int lane15 = ln & 15, quad = ln >> 4;

    __shared__ ushort Ks[256 * 40];   // [key][ch] stride 40: 20 KB
    __shared__ ushort Vt[32 * 264];   // [ch][key] stride 264: 16.5 KB
    __shared__ ushort Ps[64 * 72];    // [qrow][64key chunk]: 9 KB

    const int rb = (nd * 49 + p) * 4;
    int wid[4];
#pragma unroll
    for (int i = 0; i < 4; ++i) wid[i] = ridx[rb + i];

    const size_t kvband = (size_t)ndkv * 49;

    // ---- stage K: [key][32ch] bf16 ----
    {
        int pix = tid >> 2, ck = tid & 3;
#pragma unroll
        for (int i = 0; i < 4; ++i) {
            size_t trow = (kvband + wid[i]) * 64 + pix;
            bf16x8 v = *(const bf16x8*)(kvbuf + trow * 512 + h * 32 + ck * 8);
            *(bf16x8*)&Ks[(i * 64 + pix) * 40 + ck * 8] = v;
        }
    }
    // ---- stage V transposed: Vt[ch][key] ----
    {
        int key_l = (tid & 31) * 2;       // 0..62 within window
        int ch0 = (tid >> 5) * 4;         // 0..28
#pragma unroll
        for (int i = 0; i < 4; ++i) {
            size_t trow = (kvband + wid[i]) * 64;
            const ushort* g0 = kvbuf + (trow + key_l) * 512 + 256 + h * 32 + ch0;
            const ushort* g1 = g0 + 512;
            ushort4 a = *(const ushort4*)g0;
            ushort4 b = *(const ushort4*)g1;
            int kg = i * 64 + key_l;
            *(unsigned*)&Vt[(ch0 + 0) * 264 + kg] = (unsigned)a.x | ((unsigned)b.x << 16);
            *(unsigned*)&Vt[(ch0 + 1) * 264 + kg] = (unsigned)a.y | ((unsigned)b.y << 16);
            *(unsigned*)&Vt[(ch0 + 2) * 264 + kg] = (unsigned)a.z | ((unsigned)b.z << 16);
            *(unsigned*)&Vt[(ch0 + 3) * 264 + kg] = (unsigned)a.w | ((unsigned)b.w << 16);
        }
    }

    // ---- Q B-frag from global (wave's own 16 q-rows) ----
    const size_t qrow0 = (size_t)(nd * 49 + p) * 64;
    bf16x8 bQ = *(const bf16x8*)(qbuf + (qrow0 + wv * 16 + lane15) * 256 + h * 32 + quad * 8);

    __syncthreads();

    // ---- S^T = K · Q^T ----
    f32x4 st[16];
#pragma unroll
    for (int t = 0; t < 16; ++t) {
        bf16x8 aK = *(const bf16x8*)&Ks[(t * 16 + lane15) * 40 + quad * 8];
        st[t] = __builtin_amdgcn_mfma_f32_16x16x32_bf16(aK, bQ, (f32x4){0.f, 0.f, 0.f, 0.f}, 0, 0, 0);
    }

    // ---- softmax: bare exp2 (v_exp_f32), no max, norm deferred ----
    float sum = 0.f;
#pragma unroll
    for (int t = 0; t < 16; ++t)
#pragma unroll
        for (int r = 0; r < 4; ++r) {
            float e = __builtin_amdgcn_exp2f(st[t][r]);
            st[t][r] = e;
            sum += e;
        }
    sum += __shfl_xor(sum, 16);
    sum += __shfl_xor(sum, 32);
    const float inv = 1.f / sum;

    // ---- PV in 4 key-chunks of 64, unnormalized P through LDS ----
    f32x4 oacc[2] = {{0.f, 0.f, 0.f, 0.f}, {0.f, 0.f, 0.f, 0.f}};
    const int prow = (wv * 16 + lane15) * 72;
#pragma unroll
    for (int cc = 0; cc < 4; ++cc) {
#pragma unroll
        for (int tt = 0; tt < 4; ++tt) {
            int t = cc * 4 + tt;
            uint2 pk;
            pk.x = pk2bf(st[t][0], st[t][1]);
            pk.y = pk2bf(st[t][2], st[t][3]);
            *(uint2*)&Ps[prow + tt * 16 + quad * 4] = pk;
        }
#pragma unroll
        for (int kt = 0; kt < 2; ++kt) {
            bf16x8 aP = *(const bf16x8*)&Ps[prow + kt * 32 + quad * 8];
#pragma unroll
            for (int nt = 0; nt < 2; ++nt) {
                bf16x8 bV = *(const bf16x8*)&Vt[(nt * 16 + lane15) * 264 + cc * 64 + kt * 32 + quad * 8];
                oacc[nt] = __builtin_amdgcn_mfma_f32_16x16x32_bf16(aP, bV, oacc[nt], 0, 0, 0);
            }
        }
    }

    // ---- store (in-place over qbuf; wave owns exactly its 16 rows) ----
#pragma unroll
    for (int nt = 0; nt < 2; ++nt)
#pragma unroll
        for (int r = 0; r < 4; ++r) {
            int row = wv * 16 + quad * 4 + r;
            qbuf[(qrow0 + row) * 256 + h * 32 + nt * 16 + lane15] = f2bf(oacc[nt][r] * inv);
        }
}

// ---------------------------------------------------------------------------
extern "C" void kernel_launch(void* const* d_in, const int* in_sizes, int n_in,
                              void* d_out, int out_size, void* d_ws, size_t ws_size,
                              hipStream_t stream) {
    const float* x    = (const float*)d_in[0];
    const float* Wqkv = (const float*)d_in[1];
    const float* bqkv = (const float*)d_in[2];
    const float* Wo   = (const float*)d_in[3];
    const float* bo   = (const float*)d_in[4];
    float* out = (float*)d_out;

    char* ws = (char*)d_ws;
    ushort* xg    = (ushort*)ws;                    ws += (size_t)50176 * 256 * 2;
    ushort* q     = (ushort*)ws;                    ws += (size_t)50176 * 256 * 2;
    ushort* kv    = (ushort*)ws;                    ws += (size_t)50176 * 512 * 2;
    ushort* Wqkvt = (ushort*)ws;                    ws += (size_t)768 * 256 * 2;
    ushort* Wot   = (ushort*)ws;                    ws += (size_t)256 * 256 * 2;
    float*  xmean = (float*)ws;                     ws += (size_t)784 * 256 * 4;
    float*  qwin  = (float*)ws;                     ws += (size_t)784 * 256 * 4;
    float*  kwin  = (float*)ws;                     ws += (size_t)784 * 256 * 4;
    int*    ridx  = (int*)ws;

    k_cast_w  <<<1024, 256, 0, stream>>>(Wqkv, Wo, Wqkvt, Wot);
    k_cast_x  <<<12544, 256, 0, stream>>>(x, xg);
    k_xmean   <<<784, 256, 0, stream>>>(x, xmean);
    k_winproj <<<dim3(8, 13), 256, 0, stream>>>(xmean, Wqkv, bqkv, qwin, kwin);
    k_route   <<<784, 64, 0, stream>>>(qwin, kwin, ridx);
    k_gemm_qkv<<<dim3(6, 392), 256, 0, stream>>>(xg, Wqkvt, bqkv, q, kv);
    k_attn    <<<dim3(8, 49, 16), 256, 0, stream>>>(q, kv, ridx);
    k_gemm_o  <<<dim3(2, 392), 256, 0, stream>>>(q, Wot, bo, out);
}